// Round 9
// baseline (109.511 us; speedup 1.0000x reference)
//
#include <hip/hip_runtime.h>
#include <hip/hip_bf16.h>

#define B_ 8
#define C_ 64
#define OUT_ 64
#define KS_ 16
#define NS_ 4096
#define K_ 32
#define G_ 8   // support points (n) per block

typedef short bf16x8 __attribute__((ext_vector_type(8)));
typedef float f32x4 __attribute__((ext_vector_type(4)));

__device__ inline short f2bf(float f) {
    union { __hip_bfloat16 h; short s; } u;
    u.h = __float2bfloat16(f);
    return u.s;
}

// s_F swizzle: row bits (>>11) spread reads; kc bits (>>7) spread writes.
__device__ inline int swzF(int byte) {
    return byte ^ ((((byte >> 11) & 7) << 4) | (((byte >> 7) & 3) << 5));
}

// one-time setup: blocks 0-255 transpose weight -> Wt bf16 [64][1024];
// block 256 collapses layer 1.
__global__ __launch_bounds__(256) void setup_kernel(
    const float* __restrict__ w, short* __restrict__ wt,
    const float* __restrict__ W1, const float* __restrict__ b1,
    const float* __restrict__ centers, float* __restrict__ w1c) {
    int bid = blockIdx.x;
    if (bid < 256) {
        int idx = bid * 256 + threadIdx.x;   // 65536 total
        int j = idx >> 6, o = idx & 63;
        wt[o * 1024 + j] = f2bf(w[idx]);
    } else {
        int i = threadIdx.x;
        if (i < 16) {
            float s0 = 0.f, s1 = 0.f, s2 = 0.f, c = b1[i];
            for (int s = 0; s < 16; ++s) {
                s0 += W1[i * 48 + s];
                s1 += W1[i * 48 + 16 + s];
                s2 += W1[i * 48 + 32 + s];
            }
            for (int j = 0; j < 48; ++j) c -= W1[i * 48 + j] * centers[j];
            ((float4*)w1c)[i] = make_float4(s0, s1, s2, c);
        }
    }
}

__global__ __launch_bounds__(256, 6) void convpoint_kernel(
    const float* __restrict__ input,      // (B,C,NS,K)
    const float* __restrict__ points,     // (B,3,NS,K)
    const float* __restrict__ support,    // (B,3,NS)
    const short* __restrict__ Wt,         // (OUT,1024) bf16, transposed weight
    const float* __restrict__ W1c,        // (16,4) collapsed layer-1
    const float* __restrict__ bias,       // (OUT)
    const float* __restrict__ W2, const float* __restrict__ b2,
    const float* __restrict__ W3, const float* __restrict__ b3,
    float* __restrict__ out0,             // (B,OUT,NS)
    float* __restrict__ out1)             // (B,3,NS)
{
    // [n][m][k] bf16, byte-swizzle ^((m&7)<<4); row stride 64B   (8 KB)
    __shared__ short s_mat[G_ * KS_ * K_];
    // [n][j] bf16, j=c*16+m, swizzle swzF; row stride 2048B      (16 KB)
    __shared__ short s_F[G_ * 1024];

    const int tid = threadIdx.x;
    const int bidx = blockIdx.x;
    const int b = bidx / (NS_ / G_);
    const int n0 = (bidx % (NS_ / G_)) * G_;

    const int wave = tid >> 6;
    const int lane = tid & 63;

    // ---- output 1: pass-through support_points (independent) ----
    if (tid < 3 * G_) {
        int d = tid >> 3, g = tid & 7;
        int idx = (b * 3 + d) * NS_ + n0 + g;
        out1[idx] = support[idx];
    }

    // ---- Phase A+B: normalize + collapsed 3-layer MLP, 1 point/thread ----
    // thread = (nl = tid>>5, kl = tid&31); weights via uniform s_loads
    {
        const int nl = tid >> 5;
        const int kl = tid & 31;
        const int n = n0 + nl;
        float p0 = points[((size_t)(b * 3 + 0) * NS_ + n) * K_ + kl] - support[(b * 3 + 0) * NS_ + n];
        float p1 = points[((size_t)(b * 3 + 1) * NS_ + n) * K_ + kl] - support[(b * 3 + 1) * NS_ + n];
        float p2 = points[((size_t)(b * 3 + 2) * NS_ + n) * K_ + kl] - support[(b * 3 + 2) * NS_ + n];
        float r2 = p0 * p0 + p1 * p1 + p2 * p2;
        #pragma unroll
        for (int m2 = 1; m2 < 32; m2 <<= 1)
            r2 = fmaxf(r2, __shfl_xor(r2, m2, 64));
        float maxi = sqrtf(r2);
        float inv = (maxi == 0.f) ? 1.f : 1.f / maxi;
        p0 *= inv; p1 *= inv; p2 *= inv;

        float h1[16];
        #pragma unroll
        for (int i = 0; i < 16; ++i) {
            float4 w = ((const float4*)W1c)[i];          // uniform -> SGPR
            h1[i] = fmaxf(w.x * p0 + w.y * p1 + w.z * p2 + w.w, 0.f);
        }
        float h2[16];
        #pragma unroll
        for (int i = 0; i < 16; ++i) {
            float a = b2[i];
            #pragma unroll
            for (int j = 0; j < 16; ++j)
                a += h1[j] * W2[i * 16 + j];             // uniform -> SGPR
            h2[i] = fmaxf(a, 0.f);
        }
        #pragma unroll
        for (int i = 0; i < 16; ++i) {
            float a = b3[i];
            #pragma unroll
            for (int j = 0; j < 16; ++j)
                a += h2[j] * W3[i * 16 + j];
            a = fmaxf(a, 0.f);
            int off = nl * 1024 + i * 64 + kl * 2;       // bytes
            *(short*)((char*)s_mat + (off ^ ((i & 7) << 4))) = f2bf(a);
        }
    }
    __syncthreads();

    // ---- Phase C (MFMA): F[n][c*16+m] = sum_k input[b,c,n,k] * mat[n][k][m] ----
    // wave w: n = 2w, 2w+1; per n: B-frag from s_mat, 4 c-tiles of A from global
    {
        const int m15 = lane & 15;
        const int kc = lane >> 4;        // k-chunk: k = kc*8 + e
        #pragma unroll
        for (int i = 0; i < 2; ++i) {
            const int nl = wave * 2 + i;
            const int n = n0 + nl;
            int boff = nl * 1024 + m15 * 64 + kc * 16;       // bytes
            bf16x8 bfrag = *(const bf16x8*)((const char*)s_mat + (boff ^ ((m15 & 7) << 4)));
            #pragma unroll
            for (int ct = 0; ct < 4; ++ct) {
                const int c = ct * 16 + m15;                 // A row
                const float* ap = input + ((size_t)(b * C_ + c) * NS_ + n) * K_ + kc * 8;
                float av[8];
                *(float4*)(av)     = *(const float4*)(ap);
                *(float4*)(av + 4) = *(const float4*)(ap + 4);
                bf16x8 afrag;
                #pragma unroll
                for (int e = 0; e < 8; ++e) afrag[e] = f2bf(av[e]);
                f32x4 acc = {0.f, 0.f, 0.f, 0.f};
                acc = __builtin_amdgcn_mfma_f32_16x16x32_bf16(afrag, bfrag, acc, 0, 0, 0);
                // D: col m = lane&15, row c' = ct*16 + kc*4 + r
                #pragma unroll
                for (int r = 0; r < 4; ++r) {
                    int cc = ct * 16 + kc * 4 + r;
                    int j = cc * 16 + m15;
                    int off = nl * 2048 + j * 2;             // bytes
                    *(short*)((char*)s_F + swzF(off)) = f2bf(acc[r]);
                }
            }
        }
    }
    __syncthreads();

    // ---- Phase D (MFMA): out[n][o] = (sum_j F[n][j] * Wt[o][j])/32 + bias[o] ----
    // GEMM M=8(n, rows 8-15 duplicated/ignored) N=16(o per wave) K=1024
    {
        const int m15 = lane & 15;
        const int kc = lane >> 4;
        const int o = wave * 16 + m15;
        const int arow = m15 & 7;        // A rows 8-15 duplicate 0-7 (rows independent)
        f32x4 acc0 = {0.f, 0.f, 0.f, 0.f};
        f32x4 acc1 = {0.f, 0.f, 0.f, 0.f};
        const short* wrow = Wt + o * 1024;
        #pragma unroll
        for (int ks = 0; ks < 32; ++ks) {
            const int j0 = kc * 8 + ks * 32;
            int aoff = arow * 2048 + j0 * 2;                 // bytes
            bf16x8 af = *(const bf16x8*)((const char*)s_F + swzF(aoff));
            bf16x8 bf = *(const bf16x8*)(wrow + j0);
            if (ks & 1) acc1 = __builtin_amdgcn_mfma_f32_16x16x32_bf16(af, bf, acc1, 0, 0, 0);
            else        acc0 = __builtin_amdgcn_mfma_f32_16x16x32_bf16(af, bf, acc0, 0, 0, 0);
        }
        // D rows: n = kc*4 + r; only kc<2 (n=0..7) are valid
        if (kc < 2) {
            const float bo = bias[o];
            float4 ov;
            ov.x = (acc0[0] + acc1[0]) * (1.f / 32.f) + bo;
            ov.y = (acc0[1] + acc1[1]) * (1.f / 32.f) + bo;
            ov.z = (acc0[2] + acc1[2]) * (1.f / 32.f) + bo;
            ov.w = (acc0[3] + acc1[3]) * (1.f / 32.f) + bo;
            *(float4*)&out0[(size_t)(b * OUT_ + o) * NS_ + n0 + kc * 4] = ov;
        }
    }
}

extern "C" void kernel_launch(void* const* d_in, const int* in_sizes, int n_in,
                              void* d_out, int out_size, void* d_ws, size_t ws_size,
                              hipStream_t stream) {
    const float* input   = (const float*)d_in[0];
    const float* points  = (const float*)d_in[1];
    const float* support = (const float*)d_in[2];
    const float* weight  = (const float*)d_in[3];
    const float* bias    = (const float*)d_in[4];
    const float* centers = (const float*)d_in[5];
    const float* W1 = (const float*)d_in[6];
    const float* b1 = (const float*)d_in[7];
    const float* W2 = (const float*)d_in[8];
    const float* b2 = (const float*)d_in[9];
    const float* W3 = (const float*)d_in[10];
    const float* b3 = (const float*)d_in[11];

    float* out0 = (float*)d_out;
    float* out1 = out0 + (size_t)B_ * OUT_ * NS_;

    short* wt  = (short*)d_ws;                       // 128 KB
    float* w1c = (float*)((char*)d_ws + 131072);     // 256 B
    setup_kernel<<<257, 256, 0, stream>>>(weight, wt, W1, b1, centers, w1c);

    dim3 grid(B_ * (NS_ / G_));
    convpoint_kernel<<<grid, 256, 0, stream>>>(
        input, points, support, wt, w1c, bias,
        W2, b2, W3, b3, out0, out1);
}

// Round 10
// 100.209 us; speedup vs baseline: 1.0928x; 1.0928x over previous
//
#include <hip/hip_runtime.h>
#include <hip/hip_bf16.h>

#define B_ 8
#define C_ 64
#define OUT_ 64
#define KS_ 16
#define NS_ 4096
#define K_ 32
#define G_ 16   // support points (n) per block

typedef short bf16x8 __attribute__((ext_vector_type(8)));
typedef float f32x4 __attribute__((ext_vector_type(4)));
typedef float f32x2 __attribute__((ext_vector_type(2)));

__device__ inline short f2bf(float f) {
    union { __hip_bfloat16 h; short s; } u;
    u.h = __float2bfloat16(f);
    return u.s;
}

__device__ inline f32x2 relu2(f32x2 v) {
    v.x = fmaxf(v.x, 0.f);
    v.y = fmaxf(v.y, 0.f);
    return v;
}

// s_F swizzle: row bits (>>11) spread reads; kc bits (>>7) spread writes.
__device__ inline int swzF(int byte) {
    return byte ^ ((((byte >> 11) & 7) << 4) | (((byte >> 7) & 3) << 5));
}

// ======================= SPLIT PATH =======================
// K1: per-point MLP -> mat2[(b*NS+n)*16+m][k] bf16 (B-fragment-ready layout);
// also: weight transpose (blocks 0-255), W1c collapse per block, out1 copy.
__global__ __launch_bounds__(256) void mlp_kernel(
    const float* __restrict__ points,     // (B,3,NS,K)
    const float* __restrict__ support,    // (B,3,NS)
    const float* __restrict__ weight,     // (1024,64) f32
    short* __restrict__ wt,               // out: (64,1024) bf16
    const float* __restrict__ W1, const float* __restrict__ b1,
    const float* __restrict__ centers,
    const float* __restrict__ W2, const float* __restrict__ b2,
    const float* __restrict__ W3, const float* __restrict__ b3,
    short* __restrict__ mat2,             // out: (B*NS,16,32) bf16
    float* __restrict__ out1)             // (B,3,NS)
{
    __shared__ float s_w1c[64];
    const int tid = threadIdx.x;
    const int bidx = blockIdx.x;

    // per-block collapsed layer-1 into LDS
    if (tid < 16) {
        int i = tid;
        float s0 = 0.f, s1 = 0.f, s2 = 0.f, c = b1[i];
        for (int s = 0; s < 16; ++s) {
            s0 += W1[i * 48 + s];
            s1 += W1[i * 48 + 16 + s];
            s2 += W1[i * 48 + 32 + s];
        }
        for (int j = 0; j < 48; ++j) c -= W1[i * 48 + j] * centers[j];
        ((float4*)s_w1c)[i] = make_float4(s0, s1, s2, c);
    }
    // weight transpose chunk (blocks 0-255); wt consumed only by conv_kernel
    if (bidx < 256) {
        int idx = bidx * 256 + tid;
        wt[(idx & 63) * 1024 + (idx >> 6)] = f2bf(weight[idx]);
    }

    const int b = bidx / (NS_ / G_);
    const int n0 = (bidx % (NS_ / G_)) * G_;

    // out1 passthrough
    if (tid < 3 * G_) {
        int d = tid >> 4, g = tid & 15;
        int idx = (b * 3 + d) * NS_ + n0 + g;
        out1[idx] = support[idx];
    }
    __syncthreads();

    // MLP, 2 points packed f32x2 per thread
    const int wave = tid >> 6;
    const int lane = tid & 63;
    const int half = lane >> 5;
    const int kl = lane & 31;
    const int nla = 2 * wave + half;
    const int nlb = nla + 8;
    const int na = n0 + nla, nb = n0 + nlb;

    f32x2 p[3];
    f32x2 r2 = {0.f, 0.f};
    #pragma unroll
    for (int d = 0; d < 3; ++d) {
        const float* pp = points + (size_t)(b * 3 + d) * NS_ * K_;
        const float* sp = support + (b * 3 + d) * NS_;
        p[d].x = pp[(size_t)na * K_ + kl] - sp[na];
        p[d].y = pp[(size_t)nb * K_ + kl] - sp[nb];
        r2 += p[d] * p[d];
    }
    float r2a = r2.x, r2b = r2.y;
    #pragma unroll
    for (int m2 = 1; m2 < 32; m2 <<= 1) {
        r2a = fmaxf(r2a, __shfl_xor(r2a, m2, 64));
        r2b = fmaxf(r2b, __shfl_xor(r2b, m2, 64));
    }
    float ma = sqrtf(r2a), mb = sqrtf(r2b);
    f32x2 inv;
    inv.x = (ma == 0.f) ? 1.f : 1.f / ma;
    inv.y = (mb == 0.f) ? 1.f : 1.f / mb;
    #pragma unroll
    for (int d = 0; d < 3; ++d) p[d] *= inv;

    f32x2 h1[16];
    #pragma unroll
    for (int i = 0; i < 16; ++i) {
        float4 w = ((const float4*)s_w1c)[i];        // LDS broadcast
        f32x2 a = p[0] * w.x + p[1] * w.y + p[2] * w.z + w.w;
        h1[i] = relu2(a);
    }
    f32x2 h2[16];
    #pragma unroll
    for (int i = 0; i < 16; ++i) {
        f32x2 a = b2[i];
        #pragma unroll
        for (int j = 0; j < 16; ++j)
            a += h1[j] * W2[i * 16 + j];             // uniform -> SGPR
        h2[i] = relu2(a);
    }
    #pragma unroll
    for (int i = 0; i < 16; ++i) {
        f32x2 a = b3[i];
        #pragma unroll
        for (int j = 0; j < 16; ++j)
            a += h2[j] * W3[i * 16 + j];
        a = relu2(a);
        mat2[((size_t)(b * NS_ + na) * 16 + i) * 32 + kl] = f2bf(a.x);
        mat2[((size_t)(b * NS_ + nb) * 16 + i) * 32 + kl] = f2bf(a.y);
    }
}

// K2: einsum (phase C) + final GEMM (phase D). B-frags straight from mat2.
__global__ __launch_bounds__(256, 4) void conv_kernel(
    const float* __restrict__ input,      // (B,C,NS,K)
    const short* __restrict__ mat2,       // (B*NS,16,32) bf16
    const short* __restrict__ Wt,         // (64,1024) bf16
    const float* __restrict__ bias,       // (64)
    float* __restrict__ out0)             // (B,OUT,NS)
{
    // [n][j] bf16, j=c*16+m, swizzle swzF; row stride 2048B  (32 KB)
    __shared__ short s_F[G_ * 1024];

    const int tid = threadIdx.x;
    const int bidx = blockIdx.x;
    const int b = bidx / (NS_ / G_);
    const int n0 = (bidx % (NS_ / G_)) * G_;

    const int wave = tid >> 6;
    const int lane = tid & 63;
    const int m15 = lane & 15;
    const int kc = lane >> 4;

    // ---- Phase C (MFMA): F[n][c*16+m] = sum_k input[b,c,n,k] * mat[n][k][m] ----
    #pragma unroll
    for (int i = 0; i < 4; ++i) {
        const int nl = wave * 4 + i;
        const int n = n0 + nl;
        bf16x8 bfrag = *(const bf16x8*)(mat2 + ((size_t)(b * NS_ + n) * 16 + m15) * 32 + kc * 8);
        #pragma unroll
        for (int ct = 0; ct < 4; ++ct) {
            const int c = ct * 16 + m15;                 // A row
            const float* ap = input + ((size_t)(b * C_ + c) * NS_ + n) * K_ + kc * 8;
            float av[8];
            *(float4*)(av)     = *(const float4*)(ap);
            *(float4*)(av + 4) = *(const float4*)(ap + 4);
            bf16x8 afrag;
            #pragma unroll
            for (int e = 0; e < 8; ++e) afrag[e] = f2bf(av[e]);
            f32x4 acc = {0.f, 0.f, 0.f, 0.f};
            acc = __builtin_amdgcn_mfma_f32_16x16x32_bf16(afrag, bfrag, acc, 0, 0, 0);
            // D: col m = lane&15, row c' = ct*16 + kc*4 + r
            #pragma unroll
            for (int r = 0; r < 4; ++r) {
                int cc = ct * 16 + kc * 4 + r;
                int j = cc * 16 + m15;
                int off = nl * 2048 + j * 2;             // bytes
                *(short*)((char*)s_F + swzF(off)) = f2bf(acc[r]);
            }
        }
    }
    __syncthreads();

    // ---- Phase D (MFMA): out[n][o] = (sum_j F[n][j] * Wt[o][j])/32 + bias[o] ----
    {
        const int o = wave * 16 + m15;
        f32x4 acc0 = {0.f, 0.f, 0.f, 0.f};
        f32x4 acc1 = {0.f, 0.f, 0.f, 0.f};
        const short* wrow = Wt + o * 1024;
        #pragma unroll
        for (int ks = 0; ks < 32; ++ks) {
            const int j0 = kc * 8 + ks * 32;
            int aoff = m15 * 2048 + j0 * 2;              // bytes; n = m15
            bf16x8 af = *(const bf16x8*)((const char*)s_F + swzF(aoff));
            bf16x8 bf = *(const bf16x8*)(wrow + j0);
            if (ks & 1) acc1 = __builtin_amdgcn_mfma_f32_16x16x32_bf16(af, bf, acc1, 0, 0, 0);
            else        acc0 = __builtin_amdgcn_mfma_f32_16x16x32_bf16(af, bf, acc0, 0, 0, 0);
        }
        const float bo = bias[o];
        float4 ov;
        ov.x = (acc0[0] + acc1[0]) * (1.f / 32.f) + bo;
        ov.y = (acc0[1] + acc1[1]) * (1.f / 32.f) + bo;
        ov.z = (acc0[2] + acc1[2]) * (1.f / 32.f) + bo;
        ov.w = (acc0[3] + acc1[3]) * (1.f / 32.f) + bo;
        *(float4*)&out0[(size_t)(b * OUT_ + o) * NS_ + n0 + kc * 4] = ov;
    }
}

// ======================= FUSED FALLBACK (R8, proven 92.6 us) =======================
__global__ __launch_bounds__(256) void setup_kernel(
    const float* __restrict__ w, short* __restrict__ wt,
    const float* __restrict__ W1, const float* __restrict__ b1,
    const float* __restrict__ centers, float* __restrict__ w1c) {
    int bid = blockIdx.x;
    if (bid < 256) {
        int idx = bid * 256 + threadIdx.x;
        int j = idx >> 6, o = idx & 63;
        wt[o * 1024 + j] = f2bf(w[idx]);
    } else {
        int i = threadIdx.x;
        if (i < 16) {
            float s0 = 0.f, s1 = 0.f, s2 = 0.f, c = b1[i];
            for (int s = 0; s < 16; ++s) {
                s0 += W1[i * 48 + s];
                s1 += W1[i * 48 + 16 + s];
                s2 += W1[i * 48 + 32 + s];
            }
            for (int j = 0; j < 48; ++j) c -= W1[i * 48 + j] * centers[j];
            ((float4*)w1c)[i] = make_float4(s0, s1, s2, c);
        }
    }
}

__global__ __launch_bounds__(256) void convpoint_kernel(
    const float* __restrict__ input, const float* __restrict__ points,
    const float* __restrict__ support, const short* __restrict__ Wt,
    const float* __restrict__ W1c, const float* __restrict__ bias,
    const float* __restrict__ W2, const float* __restrict__ b2,
    const float* __restrict__ W3, const float* __restrict__ b3,
    float* __restrict__ out0, float* __restrict__ out1)
{
    __shared__ short s_mat[G_ * KS_ * K_];
    __shared__ short s_F[G_ * 1024];

    const int tid = threadIdx.x;
    const int bidx = blockIdx.x;
    const int b = bidx / (NS_ / G_);
    const int n0 = (bidx % (NS_ / G_)) * G_;
    const int wave = tid >> 6;
    const int lane = tid & 63;
    const int half = lane >> 5;
    const int kl = lane & 31;

    if (tid < 3 * G_) {
        int d = tid >> 4, g = tid & 15;
        int idx = (b * 3 + d) * NS_ + n0 + g;
        out1[idx] = support[idx];
    }
    {
        const int nla = 2 * wave + half;
        const int nlb = nla + 8;
        const int na = n0 + nla, nb = n0 + nlb;
        f32x2 p[3];
        f32x2 r2 = {0.f, 0.f};
        #pragma unroll
        for (int d = 0; d < 3; ++d) {
            const float* pp = points + (size_t)(b * 3 + d) * NS_ * K_;
            const float* sp = support + (b * 3 + d) * NS_;
            p[d].x = pp[(size_t)na * K_ + kl] - sp[na];
            p[d].y = pp[(size_t)nb * K_ + kl] - sp[nb];
            r2 += p[d] * p[d];
        }
        float r2a = r2.x, r2b = r2.y;
        #pragma unroll
        for (int m2 = 1; m2 < 32; m2 <<= 1) {
            r2a = fmaxf(r2a, __shfl_xor(r2a, m2, 64));
            r2b = fmaxf(r2b, __shfl_xor(r2b, m2, 64));
        }
        float ma = sqrtf(r2a), mb = sqrtf(r2b);
        f32x2 inv;
        inv.x = (ma == 0.f) ? 1.f : 1.f / ma;
        inv.y = (mb == 0.f) ? 1.f : 1.f / mb;
        #pragma unroll
        for (int d = 0; d < 3; ++d) p[d] *= inv;

        f32x2 h1[16];
        #pragma unroll
        for (int i = 0; i < 16; ++i) {
            float4 w = ((const float4*)W1c)[i];
            f32x2 a = p[0] * w.x + p[1] * w.y + p[2] * w.z + w.w;
            h1[i] = relu2(a);
        }
        f32x2 h2[16];
        #pragma unroll
        for (int i = 0; i < 16; ++i) {
            f32x2 a = b2[i];
            #pragma unroll
            for (int j = 0; j < 16; ++j) a += h1[j] * W2[i * 16 + j];
            h2[i] = relu2(a);
        }
        #pragma unroll
        for (int i = 0; i < 16; ++i) {
            f32x2 a = b3[i];
            #pragma unroll
            for (int j = 0; j < 16; ++j) a += h2[j] * W3[i * 16 + j];
            a = relu2(a);
            int offa = nla * 1024 + i * 64 + kl * 2;
            int offb = nlb * 1024 + i * 64 + kl * 2;
            *(short*)((char*)s_mat + (offa ^ ((i & 7) << 4))) = f2bf(a.x);
            *(short*)((char*)s_mat + (offb ^ ((i & 7) << 4))) = f2bf(a.y);
        }
    }
    __syncthreads();
    {
        const int m15 = lane & 15;
        const int kc = lane >> 4;
        #pragma unroll
        for (int i = 0; i < 4; ++i) {
            const int nl = wave * 4 + i;
            const int n = n0 + nl;
            int boff = nl * 1024 + m15 * 64 + kc * 16;
            bf16x8 bfrag = *(const bf16x8*)((const char*)s_mat + (boff ^ ((m15 & 7) << 4)));
            #pragma unroll
            for (int ct = 0; ct < 4; ++ct) {
                const int c = ct * 16 + m15;
                const float* ap = input + ((size_t)(b * C_ + c) * NS_ + n) * K_ + kc * 8;
                float av[8];
                *(float4*)(av)     = *(const float4*)(ap);
                *(float4*)(av + 4) = *(const float4*)(ap + 4);
                bf16x8 afrag;
                #pragma unroll
                for (int e = 0; e < 8; ++e) afrag[e] = f2bf(av[e]);
                f32x4 acc = {0.f, 0.f, 0.f, 0.f};
                acc = __builtin_amdgcn_mfma_f32_16x16x32_bf16(afrag, bfrag, acc, 0, 0, 0);
                #pragma unroll
                for (int r = 0; r < 4; ++r) {
                    int cc = ct * 16 + kc * 4 + r;
                    int j = cc * 16 + m15;
                    int off = nl * 2048 + j * 2;
                    *(short*)((char*)s_F + swzF(off)) = f2bf(acc[r]);
                }
            }
        }
    }
    __syncthreads();
    {
        const int m15 = lane & 15;
        const int kc = lane >> 4;
        const int o = wave * 16 + m15;
        f32x4 acc0 = {0.f, 0.f, 0.f, 0.f};
        f32x4 acc1 = {0.f, 0.f, 0.f, 0.f};
        const short* wrow = Wt + o * 1024;
        #pragma unroll
        for (int ks = 0; ks < 32; ++ks) {
            const int j0 = kc * 8 + ks * 32;
            int aoff = m15 * 2048 + j0 * 2;
            bf16x8 af = *(const bf16x8*)((const char*)s_F + swzF(aoff));
            bf16x8 bf = *(const bf16x8*)(wrow + j0);
            if (ks & 1) acc1 = __builtin_amdgcn_mfma_f32_16x16x32_bf16(af, bf, acc1, 0, 0, 0);
            else        acc0 = __builtin_amdgcn_mfma_f32_16x16x32_bf16(af, bf, acc0, 0, 0, 0);
        }
        const float bo = bias[o];
        float4 ov;
        ov.x = (acc0[0] + acc1[0]) * (1.f / 32.f) + bo;
        ov.y = (acc0[1] + acc1[1]) * (1.f / 32.f) + bo;
        ov.z = (acc0[2] + acc1[2]) * (1.f / 32.f) + bo;
        ov.w = (acc0[3] + acc1[3]) * (1.f / 32.f) + bo;
        *(float4*)&out0[(size_t)(b * OUT_ + o) * NS_ + n0 + kc * 4] = ov;
    }
}

extern "C" void kernel_launch(void* const* d_in, const int* in_sizes, int n_in,
                              void* d_out, int out_size, void* d_ws, size_t ws_size,
                              hipStream_t stream) {
    const float* input   = (const float*)d_in[0];
    const float* points  = (const float*)d_in[1];
    const float* support = (const float*)d_in[2];
    const float* weight  = (const float*)d_in[3];
    const float* bias    = (const float*)d_in[4];
    const float* centers = (const float*)d_in[5];
    const float* W1 = (const float*)d_in[6];
    const float* b1 = (const float*)d_in[7];
    const float* W2 = (const float*)d_in[8];
    const float* b2 = (const float*)d_in[9];
    const float* W3 = (const float*)d_in[10];
    const float* b3 = (const float*)d_in[11];

    float* out0 = (float*)d_out;
    float* out1 = out0 + (size_t)B_ * OUT_ * NS_;

    short* wt  = (short*)d_ws;                        // 128 KB
    float* w1c = (float*)((char*)d_ws + 131072);      // 256 B
    const size_t WS_NEED = 262144 + (size_t)B_ * NS_ * 16 * 32 * 2;  // ~34 MB

    dim3 grid(B_ * (NS_ / G_));   // 2048
    if (ws_size >= WS_NEED) {
        short* mat2 = (short*)((char*)d_ws + 262144);
        mlp_kernel<<<grid, 256, 0, stream>>>(
            points, support, weight, wt, W1, b1, centers,
            W2, b2, W3, b3, mat2, out1);
        conv_kernel<<<grid, 256, 0, stream>>>(input, mat2, wt, bias, out0);
    } else {
        setup_kernel<<<257, 256, 0, stream>>>(weight, wt, W1, b1, centers, w1c);
        convpoint_kernel<<<grid, 256, 0, stream>>>(
            input, points, support, wt, w1c, bias,
            W2, b2, W3, b3, out0, out1);
    }
}

// Round 11
// 84.297 us; speedup vs baseline: 1.2991x; 1.1888x over previous
//
#include <hip/hip_runtime.h>
#include <hip/hip_bf16.h>

#define B_ 8
#define C_ 64
#define OUT_ 64
#define KS_ 16
#define NS_ 4096
#define K_ 32
#define G_ 16   // support points (n) per block

typedef short bf16x8 __attribute__((ext_vector_type(8)));
typedef float f32x4 __attribute__((ext_vector_type(4)));
typedef float f32x2 __attribute__((ext_vector_type(2)));

__device__ inline short f2bf(float f) {
    union { __hip_bfloat16 h; short s; } u;
    u.h = __float2bfloat16(f);
    return u.s;
}

__device__ inline f32x2 relu2(f32x2 v) {
    v.x = fmaxf(v.x, 0.f);
    v.y = fmaxf(v.y, 0.f);
    return v;
}

// s_F swizzle: row bits (>>11) spread reads; kc bits (>>7) spread writes.
__device__ inline int swzF(int byte) {
    return byte ^ ((((byte >> 11) & 7) << 4) | (((byte >> 7) & 3) << 5));
}

// one-time setup: blocks 0-255 transpose weight -> Wt bf16 [64][1024];
// block 256 collapses layer 1.
__global__ __launch_bounds__(256) void setup_kernel(
    const float* __restrict__ w, short* __restrict__ wt,
    const float* __restrict__ W1, const float* __restrict__ b1,
    const float* __restrict__ centers, float* __restrict__ w1c) {
    int bid = blockIdx.x;
    if (bid < 256) {
        int idx = bid * 256 + threadIdx.x;   // 65536 total
        int j = idx >> 6, o = idx & 63;
        wt[o * 1024 + j] = f2bf(w[idx]);
    } else {
        int i = threadIdx.x;
        if (i < 16) {
            float s0 = 0.f, s1 = 0.f, s2 = 0.f, c = b1[i];
            for (int s = 0; s < 16; ++s) {
                s0 += W1[i * 48 + s];
                s1 += W1[i * 48 + 16 + s];
                s2 += W1[i * 48 + 32 + s];
            }
            for (int j = 0; j < 48; ++j) c -= W1[i * 48 + j] * centers[j];
            ((float4*)w1c)[i] = make_float4(s0, s1, s2, c);
        }
    }
}

__global__ __launch_bounds__(256, 4) void convpoint_kernel(
    const float* __restrict__ input,      // (B,C,NS,K)
    const float* __restrict__ points,     // (B,3,NS,K)
    const float* __restrict__ support,    // (B,3,NS)
    const short* __restrict__ Wt,         // (OUT,1024) bf16, transposed weight
    const float* __restrict__ W1c,        // (16,4) collapsed layer-1
    const float* __restrict__ bias,       // (OUT)
    const float* __restrict__ W2, const float* __restrict__ b2,
    const float* __restrict__ W3, const float* __restrict__ b3,
    float* __restrict__ out0,             // (B,OUT,NS)
    float* __restrict__ out1)             // (B,3,NS)
{
    // 32 KB buffer, used twice:
    //  - phase B:  s_mat [n][m][k] bf16, byte off = nl*1024+m*64+k*2 ^ ((m&7)<<4)  (first 16 KB)
    //  - phase C/D: s_F  [n][j]    bf16, byte off = swzF(nl*2048+j*2)
    // s_mat is dead after each wave hoists its 4 B-frags to registers (extra barrier).
    __shared__ __align__(16) short s_buf[G_ * 1024];

    const int tid = threadIdx.x;
    const int bidx = blockIdx.x;
    const int b = bidx / (NS_ / G_);
    const int n0 = (bidx % (NS_ / G_)) * G_;

    const int wave = tid >> 6;
    const int lane = tid & 63;
    const int half = lane >> 5;
    const int kl = lane & 31;
    const int m15 = lane & 15;
    const int kc = lane >> 4;

    // ---- output 1: pass-through support_points (independent) ----
    if (tid < 3 * G_) {
        int d = tid >> 4, g = tid & 15;
        int idx = (b * 3 + d) * NS_ + n0 + g;
        out1[idx] = support[idx];
    }

    // ---- Phase A+B: normalize + collapsed 3-layer MLP, 2 points packed f32x2 ----
    {
        const int nla = 2 * wave + half;       // local n for point a
        const int nlb = nla + 8;               // local n for point b
        const int na = n0 + nla, nb = n0 + nlb;
        f32x2 p[3];
        f32x2 r2 = {0.f, 0.f};
        #pragma unroll
        for (int d = 0; d < 3; ++d) {
            const float* pp = points + (size_t)(b * 3 + d) * NS_ * K_;
            const float* sp = support + (b * 3 + d) * NS_;
            p[d].x = pp[(size_t)na * K_ + kl] - sp[na];
            p[d].y = pp[(size_t)nb * K_ + kl] - sp[nb];
            r2 += p[d] * p[d];
        }
        float r2a = r2.x, r2b = r2.y;
        #pragma unroll
        for (int m2 = 1; m2 < 32; m2 <<= 1) {
            r2a = fmaxf(r2a, __shfl_xor(r2a, m2, 64));
            r2b = fmaxf(r2b, __shfl_xor(r2b, m2, 64));
        }
        float ma = sqrtf(r2a), mb = sqrtf(r2b);
        f32x2 inv;
        inv.x = (ma == 0.f) ? 1.f : 1.f / ma;
        inv.y = (mb == 0.f) ? 1.f : 1.f / mb;
        #pragma unroll
        for (int d = 0; d < 3; ++d) p[d] *= inv;

        f32x2 h1[16];
        #pragma unroll
        for (int i = 0; i < 16; ++i) {
            float4 w = ((const float4*)W1c)[i];          // uniform -> SGPR
            f32x2 a = p[0] * w.x + p[1] * w.y + p[2] * w.z + w.w;
            h1[i] = relu2(a);
        }
        f32x2 h2[16];
        #pragma unroll
        for (int i = 0; i < 16; ++i) {
            f32x2 a = b2[i];
            #pragma unroll
            for (int j = 0; j < 16; ++j)
                a += h1[j] * W2[i * 16 + j];             // uniform -> SGPR, v_pk_fma
            h2[i] = relu2(a);
        }
        #pragma unroll
        for (int i = 0; i < 16; ++i) {
            f32x2 a = b3[i];
            #pragma unroll
            for (int j = 0; j < 16; ++j)
                a += h2[j] * W3[i * 16 + j];
            a = relu2(a);
            int offa = nla * 1024 + i * 64 + kl * 2;     // bytes, < 16384
            int offb = nlb * 1024 + i * 64 + kl * 2;
            *(short*)((char*)s_buf + (offa ^ ((i & 7) << 4))) = f2bf(a.x);
            *(short*)((char*)s_buf + (offb ^ ((i & 7) << 4))) = f2bf(a.y);
        }
    }
    __syncthreads();

    // ---- hoist B-frags (s_mat) to registers, then s_mat region is dead ----
    bf16x8 bfrag[4];
    #pragma unroll
    for (int i = 0; i < 4; ++i) {
        const int nl = wave * 4 + i;
        int boff = nl * 1024 + m15 * 64 + kc * 16;       // bytes, < 16384
        bfrag[i] = *(const bf16x8*)((const char*)s_buf + (boff ^ ((m15 & 7) << 4)));
    }
    __syncthreads();   // all s_mat reads complete before s_F overwrites

    // ---- Phase C (MFMA): F[n][c*16+m] = sum_k input[b,c,n,k] * mat[n][k][m] ----
    {
        #pragma unroll
        for (int i = 0; i < 4; ++i) {
            const int nl = wave * 4 + i;
            const int n = n0 + nl;
            #pragma unroll
            for (int ct = 0; ct < 4; ++ct) {
                const int c = ct * 16 + m15;                 // A row
                const float* ap = input + ((size_t)(b * C_ + c) * NS_ + n) * K_ + kc * 8;
                float av[8];
                *(float4*)(av)     = *(const float4*)(ap);
                *(float4*)(av + 4) = *(const float4*)(ap + 4);
                bf16x8 afrag;
                #pragma unroll
                for (int e = 0; e < 8; ++e) afrag[e] = f2bf(av[e]);
                f32x4 acc = {0.f, 0.f, 0.f, 0.f};
                acc = __builtin_amdgcn_mfma_f32_16x16x32_bf16(afrag, bfrag[i], acc, 0, 0, 0);
                // D: col m = lane&15, row c' = ct*16 + kc*4 + r
                #pragma unroll
                for (int r = 0; r < 4; ++r) {
                    int cc = ct * 16 + kc * 4 + r;
                    int j = cc * 16 + m15;
                    int off = nl * 2048 + j * 2;             // bytes
                    *(short*)((char*)s_buf + swzF(off)) = f2bf(acc[r]);
                }
            }
        }
    }
    __syncthreads();

    // ---- Phase D (MFMA): out[n][o] = (sum_j F[n][j] * Wt[o][j])/32 + bias[o] ----
    // GEMM M=16(n) N=16(o per wave) K=1024
    {
        const int o = wave * 16 + m15;
        f32x4 acc0 = {0.f, 0.f, 0.f, 0.f};
        f32x4 acc1 = {0.f, 0.f, 0.f, 0.f};
        const short* wrow = Wt + o * 1024;
        #pragma unroll
        for (int ks = 0; ks < 32; ++ks) {
            const int j0 = kc * 8 + ks * 32;
            int aoff = m15 * 2048 + j0 * 2;                  // bytes; n = m15
            bf16x8 af = *(const bf16x8*)((const char*)s_buf + swzF(aoff));
            bf16x8 bf = *(const bf16x8*)(wrow + j0);
            if (ks & 1) acc1 = __builtin_amdgcn_mfma_f32_16x16x32_bf16(af, bf, acc1, 0, 0, 0);
            else        acc0 = __builtin_amdgcn_mfma_f32_16x16x32_bf16(af, bf, acc0, 0, 0, 0);
        }
        const float bo = bias[o];
        float4 ov;
        ov.x = (acc0[0] + acc1[0]) * (1.f / 32.f) + bo;
        ov.y = (acc0[1] + acc1[1]) * (1.f / 32.f) + bo;
        ov.z = (acc0[2] + acc1[2]) * (1.f / 32.f) + bo;
        ov.w = (acc0[3] + acc1[3]) * (1.f / 32.f) + bo;
        // D rows: n = kc*4 + r (4 consecutive) at col o
        *(float4*)&out0[(size_t)(b * OUT_ + o) * NS_ + n0 + kc * 4] = ov;
    }
}

extern "C" void kernel_launch(void* const* d_in, const int* in_sizes, int n_in,
                              void* d_out, int out_size, void* d_ws, size_t ws_size,
                              hipStream_t stream) {
    const float* input   = (const float*)d_in[0];
    const float* points  = (const float*)d_in[1];
    const float* support = (const float*)d_in[2];
    const float* weight  = (const float*)d_in[3];
    const float* bias    = (const float*)d_in[4];
    const float* centers = (const float*)d_in[5];
    const float* W1 = (const float*)d_in[6];
    const float* b1 = (const float*)d_in[7];
    const float* W2 = (const float*)d_in[8];
    const float* b2 = (const float*)d_in[9];
    const float* W3 = (const float*)d_in[10];
    const float* b3 = (const float*)d_in[11];

    float* out0 = (float*)d_out;
    float* out1 = out0 + (size_t)B_ * OUT_ * NS_;

    short* wt  = (short*)d_ws;                       // 128 KB
    float* w1c = (float*)((char*)d_ws + 131072);     // 256 B
    setup_kernel<<<257, 256, 0, stream>>>(weight, wt, W1, b1, centers, w1c);

    dim3 grid(B_ * (NS_ / G_));
    convpoint_kernel<<<grid, 256, 0, stream>>>(
        input, points, support, wt, w1c, bias,
        W2, b2, W3, b3, out0, out1);
}